// Round 5
// baseline (278.140 us; speedup 1.0000x reference)
//
#include <hip/hip_runtime.h>

#define VOCAB 100000
#define DIM 128
#define BATCH 262144
#define NEG 5

#define NBLOCK 2048
#define NTHREADS 256
#define WAVES_PER_BLOCK 4
#define NWAVES (NBLOCK * WAVES_PER_BLOCK)   // 8192 waves
#define NPAIRS (BATCH / 2)                  // 131072 element-pairs
#define NIT (NPAIRS / NWAVES)               // 16 iterations/wave, exact

// log(1 + exp(x)); scores here are |x| <~ 0.02 so exp(-|x|) ~ 1 and the
// plain logf(1+z) form has no cancellation risk.
__device__ __forceinline__ float softplus_fast(float x) {
    return fmaxf(x, 0.0f) + __logf(1.0f + __expf(-fabsf(x)));
}

__device__ __forceinline__ float dot4(float4 a, float4 b) {
    return a.x * b.x + a.y * b.y + a.z * b.z + a.w * b.w;
}

// async global->LDS, 16B per lane. LDS dest is wave-uniform base + lane*16;
// global source is per-lane.
__device__ __forceinline__ void async_row16(const float* gsrc, float* ldst) {
    __builtin_amdgcn_global_load_lds(
        (const __attribute__((address_space(1))) void*)gsrc,
        (__attribute__((address_space(3))) void*)ldst,
        16, 0, 0);
}

__global__ void ns_init_kernel(float* acc) {
    acc[0] = 0.0f;
    acc[1] = 0.0f;
}

__global__ __launch_bounds__(NTHREADS) void ns_loss_kernel(
    const int* __restrict__ tgt,
    const int* __restrict__ ctx,
    const int* __restrict__ negw,
    const float* __restrict__ iemb,
    const float* __restrict__ oemb,
    float* __restrict__ acc)
{
    // [wave][dbuf][slot 0..6][elem-half 0|1][128 floats] = 56 KB
    __shared__ __align__(16) float lds[WAVES_PER_BLOCK][2][7][2][128];

    const int tid  = threadIdx.x;
    const int lane = tid & 63;
    const int w    = tid >> 6;
    const int l    = lane & 31;   // 16B chunk within a 512B row
    const int h    = lane >> 5;   // which of the pair's 2 elements
    const int W    = blockIdx.x * WAVES_PER_BLOCK + w;

    float pos_acc = 0.0f, neg_acc = 0.0f;

    int ix[7];  // row words for the NEXT DMA: [t, c, n0..n4], per-lane (h-dep)

    // ---- prologue: indices for it=0, DMA it=0 -> buf0, indices for it=1
    {
        const int e = (W) * 2 + h;
        ix[0] = tgt[e];
        ix[1] = ctx[e];
        #pragma unroll
        for (int j = 0; j < NEG; ++j) ix[2 + j] = negw[e * NEG + j];
    }
    {
        float* nbuf = &lds[w][0][0][0][0];
        async_row16(iemb + (size_t)ix[0] * DIM + l * 4, nbuf + 0 * 256);
        #pragma unroll
        for (int k = 1; k < 7; ++k)
            async_row16(oemb + (size_t)ix[k] * DIM + l * 4, nbuf + k * 256);
    }
    {
        const int e = (W + NWAVES) * 2 + h;
        ix[0] = tgt[e];
        ix[1] = ctx[e];
        #pragma unroll
        for (int j = 0; j < NEG; ++j) ix[2 + j] = negw[e * NEG + j];
    }

    // ---- main loop: per wave, no barriers (private LDS region)
    for (int it = 0; it < NIT; ++it) {
        // drain: DMA(it) done (compute input ready) AND idx(it+1) regs ready
        asm volatile("s_waitcnt vmcnt(0)" ::: "memory");

        // issue next tile's DMA (7 KB in flight across this iter's compute)
        if (it + 1 < NIT) {
            float* nbuf = &lds[w][(it + 1) & 1][0][0][0];
            async_row16(iemb + (size_t)ix[0] * DIM + l * 4, nbuf + 0 * 256);
            #pragma unroll
            for (int k = 1; k < 7; ++k)
                async_row16(oemb + (size_t)ix[k] * DIM + l * 4, nbuf + k * 256);
        }
        // prefetch indices two iterations ahead
        if (it + 2 < NIT) {
            const int e = (W + (it + 2) * NWAVES) * 2 + h;
            ix[0] = tgt[e];
            ix[1] = ctx[e];
            #pragma unroll
            for (int j = 0; j < NEG; ++j) ix[2 + j] = negw[e * NEG + j];
        }

        // ---- compute on current buffer: 32 lanes per element
        const float* rbase = &lds[w][it & 1][0][h][l * 4];
        const float4 t4 = *(const float4*)(rbase + 0 * 256);
        const float4 c4 = *(const float4*)(rbase + 1 * 256);
        float dp = dot4(t4, c4);
        float dn[NEG];
        #pragma unroll
        for (int j = 0; j < NEG; ++j) {
            const float4 n4 = *(const float4*)(rbase + (2 + j) * 256);
            dn[j] = dot4(t4, n4);
        }

        // butterfly over the 32-lane group (masks <=16 stay within group)
        #pragma unroll
        for (int m = 16; m >= 1; m >>= 1) {
            dp += __shfl_xor(dp, m, 64);
            #pragma unroll
            for (int j = 0; j < NEG; ++j) dn[j] += __shfl_xor(dn[j], m, 64);
        }

        // all 32 lanes of each group accumulate (32x redundant; divided out)
        pos_acc += softplus_fast(-dp);             // -log_sigmoid(+dp)
        float s = 0.0f;
        #pragma unroll
        for (int j = 0; j < NEG; ++j) s += softplus_fast(dn[j]);  // -log_sigmoid(-dn)
        neg_acc += s;
    }

    // ---- full-wave reduce, one atomic pair per wave
    #pragma unroll
    for (int m = 32; m >= 1; m >>= 1) {
        pos_acc += __shfl_xor(pos_acc, m, 64);
        neg_acc += __shfl_xor(neg_acc, m, 64);
    }
    if (lane == 0) {
        atomicAdd(&acc[0], pos_acc);
        atomicAdd(&acc[1], neg_acc);
    }
}

__global__ void ns_finalize_kernel(const float* __restrict__ acc, float* __restrict__ out) {
    // each element's loss was accumulated by its 32-lane group
    out[0] = acc[0] * (1.0f / ((float)BATCH * 32.0f));
    out[1] = acc[1] * (1.0f / ((float)BATCH * (float)NEG * 32.0f));
}

extern "C" void kernel_launch(void* const* d_in, const int* in_sizes, int n_in,
                              void* d_out, int out_size, void* d_ws, size_t ws_size,
                              hipStream_t stream) {
    const int*   tgt  = (const int*)d_in[0];
    const int*   ctx  = (const int*)d_in[1];
    const int*   negw = (const int*)d_in[2];
    const float* iemb = (const float*)d_in[3];
    const float* oemb = (const float*)d_in[4];
    float* out = (float*)d_out;
    float* acc = (float*)d_ws;

    ns_init_kernel<<<1, 1, 0, stream>>>(acc);
    ns_loss_kernel<<<NBLOCK, NTHREADS, 0, stream>>>(tgt, ctx, negw, iemb, oemb, acc);
    ns_finalize_kernel<<<1, 1, 0, stream>>>(acc, out);
}

// Round 6
// 266.631 us; speedup vs baseline: 1.0432x; 1.0432x over previous
//
#include <hip/hip_runtime.h>

typedef _Float16 f16;
typedef _Float16 f16x2 __attribute__((ext_vector_type(2)));
typedef _Float16 f16x4 __attribute__((ext_vector_type(4)));

#define VOCAB 100000
#define DIM 128
#define BATCH 262144
#define NEG 5

#define NBLOCK 2048
#define NTHREADS 256
#define GROUPS_PER_BLOCK (NTHREADS / 16)      // 16-lane groups
#define NGROUPS (NBLOCK * GROUPS_PER_BLOCK)   // 32768
#define EPG (BATCH / NGROUPS)                 // 8 elements per group, exact

#define TABLE_HALF_BYTES ((size_t)VOCAB * DIM * 2)            // 25.6 MB
#define WS_NEEDED (256 + 2 * TABLE_HALF_BYTES)                // acc + 2 tables

// log(1 + exp(x)); |x| <~ 0.02 here so exp(-|x|) ~ 1: no cancellation risk.
__device__ __forceinline__ float softplus_fast(float x) {
    return fmaxf(x, 0.0f) + __logf(1.0f + __expf(-fabsf(x)));
}

__device__ __forceinline__ float fdot2h(f16x2 a, f16x2 b, float c) {
#if __has_builtin(__builtin_amdgcn_fdot2)
    return __builtin_amdgcn_fdot2(a, b, c, false);
#else
    return c + (float)a[0] * (float)b[0] + (float)a[1] * (float)b[1];
#endif
}

// dot of 8 halves (one dwordx4 each side), fp32 accumulate
__device__ __forceinline__ float dot8h(uint4 a, uint4 b, float s) {
    union { uint4 u; f16x2 h[4]; } A, B;
    A.u = a; B.u = b;
    #pragma unroll
    for (int i = 0; i < 4; ++i) s = fdot2h(A.h[i], B.h[i], s);
    return s;
}

__global__ void ns_init_kernel(float* acc) {
    acc[0] = 0.0f;
    acc[1] = 0.0f;
}

// ---- streaming fp32 -> fp16 conversion of both tables (153.6 MB total) ----
__global__ __launch_bounds__(256) void ns_convert_kernel(
    const float* __restrict__ iemb, const float* __restrict__ oemb,
    f16* __restrict__ iembH, f16* __restrict__ oembH)
{
    const int n4 = VOCAB * DIM / 4;   // 3.2M float4 per table
    int i = blockIdx.x * blockDim.x + threadIdx.x;
    const int stride = gridDim.x * blockDim.x;
    for (; i < n4; i += stride) {
        float4 a = reinterpret_cast<const float4*>(iemb)[i];
        f16x4 ha = {(f16)a.x, (f16)a.y, (f16)a.z, (f16)a.w};
        reinterpret_cast<f16x4*>(iembH)[i] = ha;
        float4 b = reinterpret_cast<const float4*>(oemb)[i];
        f16x4 hb = {(f16)b.x, (f16)b.y, (f16)b.z, (f16)b.w};
        reinterpret_cast<f16x4*>(oembH)[i] = hb;
    }
}

// ---- fp16-gather loss kernel, register double-buffered pipeline ----
__global__ __launch_bounds__(NTHREADS) void ns_loss_h_kernel(
    const int* __restrict__ tgt,
    const int* __restrict__ ctx,
    const int* __restrict__ negw,
    const f16* __restrict__ iembH,
    const f16* __restrict__ oembH,
    float* __restrict__ acc)
{
    const int tid   = threadIdx.x;
    const int lane  = tid & 63;
    const int r     = lane & 15;                         // 16B chunk within 256B row
    const int group = blockIdx.x * GROUPS_PER_BLOCK + (tid >> 4);

    float pos = 0.0f, neg = 0.0f;

    int ixA[7], ixB[7];
    uint4 A[7], B[7];

    // idx set for element `it` of this group (clamped for prefetch overrun)
    #define LOAD_IDX(it, ix)                                            \
        do {                                                            \
            int e_ = group + (it) * NGROUPS;                            \
            e_ = (e_ < BATCH) ? e_ : 0;                                 \
            (ix)[0] = tgt[e_];                                          \
            (ix)[1] = ctx[e_];                                          \
            _Pragma("unroll")                                           \
            for (int j_ = 0; j_ < NEG; ++j_)                            \
                (ix)[2 + j_] = negw[e_ * NEG + j_];                     \
        } while (0)

    // issue the 7 row loads (one dwordx4 per row per lane; group covers 256B)
    #define ISSUE_ROWS(ix, buf)                                                         \
        do {                                                                            \
            (buf)[0] = reinterpret_cast<const uint4*>(iembH + ((size_t)(ix)[0] << 7))[r]; \
            _Pragma("unroll")                                                           \
            for (int k_ = 1; k_ < 7; ++k_)                                              \
                (buf)[k_] = reinterpret_cast<const uint4*>(oembH + ((size_t)(ix)[k_] << 7))[r]; \
        } while (0)

    #define COMPUTE_E(buf)                                              \
        do {                                                            \
            float dp_ = dot8h((buf)[0], (buf)[1], 0.0f);                \
            float dn_[NEG];                                             \
            _Pragma("unroll")                                           \
            for (int j_ = 0; j_ < NEG; ++j_)                            \
                dn_[j_] = dot8h((buf)[0], (buf)[2 + j_], 0.0f);         \
            _Pragma("unroll")                                           \
            for (int m_ = 8; m_ >= 1; m_ >>= 1) {                       \
                dp_ += __shfl_xor(dp_, m_, 64);                         \
                _Pragma("unroll")                                       \
                for (int j_ = 0; j_ < NEG; ++j_)                        \
                    dn_[j_] += __shfl_xor(dn_[j_], m_, 64);             \
            }                                                           \
            pos += softplus_fast(-dp_);                                 \
            float s_ = 0.0f;                                            \
            _Pragma("unroll")                                           \
            for (int j_ = 0; j_ < NEG; ++j_)                            \
                s_ += softplus_fast(dn_[j_]);                           \
            neg += s_;                                                  \
        } while (0)

    // prologue
    LOAD_IDX(0, ixA);
    ISSUE_ROWS(ixA, A);
    LOAD_IDX(1, ixB);

    // steady state: compute(cur) overlaps rows(next) + idx(next+1) in flight
    #pragma unroll
    for (int it = 0; it < EPG; it += 2) {
        if (it + 1 < EPG) ISSUE_ROWS(ixB, B);       // rows for e_{it+1}
        if (it + 2 < EPG) LOAD_IDX(it + 2, ixA);    // idx  for e_{it+2}
        COMPUTE_E(A);                               // element it
        if (it + 2 < EPG) ISSUE_ROWS(ixA, A);       // rows for e_{it+2}
        if (it + 3 < EPG) LOAD_IDX(it + 3, ixB);    // idx  for e_{it+3}
        if (it + 1 < EPG) COMPUTE_E(B);             // element it+1
    }

    #undef LOAD_IDX
    #undef ISSUE_ROWS
    #undef COMPUTE_E

    // full-wave butterfly (sums 4 groups x 16-lane redundancy), one atomic pair
    #pragma unroll
    for (int m = 32; m >= 1; m >>= 1) {
        pos += __shfl_xor(pos, m, 64);
        neg += __shfl_xor(neg, m, 64);
    }
    if (lane == 0) {
        atomicAdd(&acc[0], pos);
        atomicAdd(&acc[1], neg);
    }
}

__global__ void ns_finalize_h_kernel(const float* __restrict__ acc, float* __restrict__ out) {
    // each element accumulated by its 16 lanes -> divide the 16x redundancy
    out[0] = acc[0] * (1.0f / ((float)BATCH * 16.0f));
    out[1] = acc[1] * (1.0f / ((float)BATCH * (float)NEG * 16.0f));
}

// ================= fp32 fallback (round-4 structure) =================
__global__ __launch_bounds__(256) void ns_loss_f32_kernel(
    const int* __restrict__ tgt, const int* __restrict__ ctx,
    const int* __restrict__ negw,
    const float* __restrict__ iemb, const float* __restrict__ oemb,
    float* __restrict__ acc)
{
    const int tid = threadIdx.x;
    const int r   = tid & 7;
    const int grp = tid >> 3;
    const int e0  = blockIdx.x * 32 + grp;
    const int estride = gridDim.x * 32;

    float pos_acc = 0.0f, neg_acc = 0.0f;
    for (int e = e0; e < BATCH; e += estride) {
        const int tw = tgt[e];
        const int cw = ctx[e];
        const float4* tp = reinterpret_cast<const float4*>(iemb + (size_t)tw * DIM) + r * 4;
        const float4 t0 = tp[0], t1 = tp[1], t2 = tp[2], t3 = tp[3];
        const float4* cp = reinterpret_cast<const float4*>(oemb + (size_t)cw * DIM) + r * 4;
        float dp = t0.x*cp[0].x+t0.y*cp[0].y+t0.z*cp[0].z+t0.w*cp[0].w
                 + t1.x*cp[1].x+t1.y*cp[1].y+t1.z*cp[1].z+t1.w*cp[1].w
                 + t2.x*cp[2].x+t2.y*cp[2].y+t2.z*cp[2].z+t2.w*cp[2].w
                 + t3.x*cp[3].x+t3.y*cp[3].y+t3.z*cp[3].z+t3.w*cp[3].w;
        float dn[NEG];
        #pragma unroll
        for (int j = 0; j < NEG; ++j) {
            const int nw = negw[e * NEG + j];
            const float4* np_ = reinterpret_cast<const float4*>(oemb + (size_t)nw * DIM) + r * 4;
            dn[j] = t0.x*np_[0].x+t0.y*np_[0].y+t0.z*np_[0].z+t0.w*np_[0].w
                  + t1.x*np_[1].x+t1.y*np_[1].y+t1.z*np_[1].z+t1.w*np_[1].w
                  + t2.x*np_[2].x+t2.y*np_[2].y+t2.z*np_[2].z+t2.w*np_[2].w
                  + t3.x*np_[3].x+t3.y*np_[3].y+t3.z*np_[3].z+t3.w*np_[3].w;
        }
        #pragma unroll
        for (int m = 4; m >= 1; m >>= 1) {
            dp += __shfl_xor(dp, m, 64);
            #pragma unroll
            for (int j = 0; j < NEG; ++j) dn[j] += __shfl_xor(dn[j], m, 64);
        }
        pos_acc += softplus_fast(-dp);
        float s = 0.0f;
        #pragma unroll
        for (int j = 0; j < NEG; ++j) s += softplus_fast(dn[j]);
        neg_acc += s;
    }
    #pragma unroll
    for (int m = 32; m >= 1; m >>= 1) {
        pos_acc += __shfl_xor(pos_acc, m, 64);
        neg_acc += __shfl_xor(neg_acc, m, 64);
    }
    if ((tid & 63) == 0) {
        atomicAdd(&acc[0], pos_acc);
        atomicAdd(&acc[1], neg_acc);
    }
}

__global__ void ns_finalize_f32_kernel(const float* __restrict__ acc, float* __restrict__ out) {
    out[0] = acc[0] * (1.0f / ((float)BATCH * 8.0f));
    out[1] = acc[1] * (1.0f / ((float)BATCH * (float)NEG * 8.0f));
}

extern "C" void kernel_launch(void* const* d_in, const int* in_sizes, int n_in,
                              void* d_out, int out_size, void* d_ws, size_t ws_size,
                              hipStream_t stream) {
    const int*   tgt  = (const int*)d_in[0];
    const int*   ctx  = (const int*)d_in[1];
    const int*   negw = (const int*)d_in[2];
    const float* iemb = (const float*)d_in[3];
    const float* oemb = (const float*)d_in[4];
    float* out = (float*)d_out;
    float* acc = (float*)d_ws;

    if (ws_size >= WS_NEEDED) {
        f16* iembH = (f16*)((char*)d_ws + 256);
        f16* oembH = (f16*)((char*)d_ws + 256 + TABLE_HALF_BYTES);
        ns_init_kernel<<<1, 1, 0, stream>>>(acc);
        ns_convert_kernel<<<2048, 256, 0, stream>>>(iemb, oemb, iembH, oembH);
        ns_loss_h_kernel<<<NBLOCK, NTHREADS, 0, stream>>>(tgt, ctx, negw, iembH, oembH, acc);
        ns_finalize_h_kernel<<<1, 1, 0, stream>>>(acc, out);
    } else {
        ns_init_kernel<<<1, 1, 0, stream>>>(acc);
        ns_loss_f32_kernel<<<2048, 256, 0, stream>>>(tgt, ctx, negw, iemb, oemb, acc);
        ns_finalize_f32_kernel<<<1, 1, 0, stream>>>(acc, out);
    }
}